// Round 4
// baseline (8050.291 us; speedup 1.0000x reference)
//
#include <hip/hip_runtime.h>
#include <math.h>

// Hierarchical RNN — round 4: persistent GRU-chain with FULLY UNROLLED chunk
// loop so h-state (hm/ha) stays in registers (R3 spilled it to scratch:
// 1.24 GB HBM traffic/dispatch from dynamic-indexed private arrays).
// N = B*ENC = 10272 rows padded to MP = 10368 = 162*64.

#define NB     10272
#define MP     10368
#define ENC_   321
#define SEQ_   720
#define PRED_  96
#define BATCH_ 32

typedef long long i64;
typedef unsigned short u16;
typedef unsigned int u32;
using bf16x8 = __attribute__((ext_vector_type(8))) short;
using f32x4  = __attribute__((ext_vector_type(4))) float;

#define AS1 __attribute__((address_space(1)))
#define AS3 __attribute__((address_space(3)))
#define GLOAD16(g, l) __builtin_amdgcn_global_load_lds((const AS1 void*)(g), (AS3 void*)(l), 16, 0, 0)

__device__ __forceinline__ float bf2f(u16 u) {
    union { u32 i; float f; } v; v.i = ((u32)u) << 16; return v.f;
}
__device__ __forceinline__ u16 f2bf(float f) {
    union { float f; u32 i; } v; v.f = f;
    return (u16)((v.i + 0x7fff + ((v.i >> 16) & 1)) >> 16);
}
__device__ __forceinline__ float sigf(float x) {
    x = fminf(fmaxf(x, -30.f), 30.f);
    return 1.f / (1.f + __expf(-x));
}
__device__ __forceinline__ float tanhfast(float x) {
    x = fminf(fmaxf(x, -15.f), 15.f);
    float e = __expf(2.f * x);
    return (e - 1.f) / (e + 1.f);
}
__device__ __forceinline__ float bsel(uint2 u, int r) {
    u32 wv = (r & 2) ? u.y : u.x;
    return bf2f((u16)((r & 1) ? (wv >> 16) : (wv & 0xffff)));
}

// ---------------------------------------------------------------- converters
__global__ __launch_bounds__(256) void convert_pad(const float* __restrict__ src,
                                                   u16* __restrict__ dst,
                                                   int R, int C, int Rp, int Cp) {
    i64 idx = (i64)blockIdx.x * 256 + threadIdx.x;
    i64 total = (i64)Rp * Cp;
    if (idx >= total) return;
    int r = (int)(idx / Cp);
    int c = (int)(idx - (i64)r * Cp);
    dst[idx] = (r < R && c < C) ? f2bf(src[(i64)r * C + c]) : (u16)0;
}

// Whh -> chain-chunk layout: chunk ci=(cg*3+g) holds rows c_local=0..31
// (global col cg*32+c_local of gate g), 16B granules XOR-swizzled by (c&7).
__global__ __launch_bounds__(256) void convert_whh_perm(const float* __restrict__ src,
                                                        u16* __restrict__ dst, int D) {
    i64 idx = (i64)blockIdx.x * 256 + threadIdx.x;
    i64 total = (i64)3 * D * D;
    if (idx >= total) return;
    int ci = (int)(idx / (32 * D));
    int rem = (int)(idx - (i64)ci * 32 * D);
    int c = rem / D;
    int p = rem - c * D;
    int phys_g = p >> 3, e = p & 7;
    int k = ((phys_g ^ (c & 7)) << 3) + e;
    int cg = ci / 3, g = ci - cg * 3;
    dst[idx] = f2bf(src[(i64)(g * D + cg * 32 + c) * D + k]);
}

__global__ __launch_bounds__(256) void seg_gather_bf(const float* __restrict__ x,
                                                     u16* __restrict__ dst,
                                                     int t0, int T, int s, int Kp) {
    i64 idx = (i64)blockIdx.x * 256 + threadIdx.x;
    i64 per_t = (i64)MP * Kp;
    i64 total = (i64)T * per_t;
    if (idx >= total) return;
    int t = (int)(idx / per_t);
    i64 rem = idx - (i64)t * per_t;
    int j = (int)(rem / MP);
    int n = (int)(rem - (i64)j * MP);
    float v = 0.f;
    if (n < NB && j < s) {
        int b = n / ENC_, e = n - b * ENC_;
        const float* xb = x + (i64)b * SEQ_ * ENC_ + e;
        v = xb[(i64)((t0 + t) * s + j) * ENC_] - xb[(i64)(SEQ_ - 1) * ENC_];
    }
    dst[((i64)t * MP + n) * Kp + j] = f2bf(v);
}

__global__ __launch_bounds__(256) void pmat_fill_bf(const float* __restrict__ pos,
                                                    const float* __restrict__ chan,
                                                    u16* __restrict__ dst,
                                                    int S, int d, int Rp) {
    i64 idx = (i64)blockIdx.x * 256 + threadIdx.x;
    i64 total = (i64)Rp * d;
    if (idx >= total) return;
    int row = (int)(idx / d);
    int c = (int)(idx - (i64)row * d);
    float v = 0.f;
    if (row < ENC_ * S) {
        int e = row / S, sy = row - e * S;
        int half = d >> 1;
        v = (c < half) ? pos[sy * half + c] : chan[e * half + (c - half)];
    }
    dst[idx] = f2bf(v);
}

__global__ __launch_bounds__(256) void out_kernel(const float* __restrict__ x,
                                                  const float* __restrict__ y0,
                                                  const float* __restrict__ y1,
                                                  float* __restrict__ out) {
    int idx = blockIdx.x * 256 + threadIdx.x;
    const int total = BATCH_ * PRED_ * ENC_;
    if (idx >= total) return;
    int b = idx / (PRED_ * ENC_);
    int r = idx - b * (PRED_ * ENC_);
    int p = r / ENC_;
    int e = r - p * ENC_;
    int n = b * ENC_ + e;
    float sl = x[(i64)b * SEQ_ * ENC_ + (i64)(SEQ_ - 1) * ENC_ + e];
    out[idx] = sl + 0.5f * (y0[(i64)n * PRED_ + p] + y1[(i64)n * PRED_ + p]);
}

// ------------------------------------------------- bf16 MFMA NT GEMM 128x128xK
// MODE: 0 fp32 natural, 1 bf16 natural, 2 bf16+relu, 3 chain-fragment layout
template<int MODE>
__global__ __launch_bounds__(256) void gemm_bf16mfma(const u16* __restrict__ A,
                                                     const u16* __restrict__ B,
                                                     const float* __restrict__ bias,
                                                     void* __restrict__ Cp,
                                                     int K, int Mstore, int Nstore,
                                                     int ldc, int dgate) {
    __shared__ u16 smA[128 * 64];
    __shared__ u16 smB[128 * 64];
    const int tid = threadIdx.x;
    const int w = tid >> 6, l = tid & 63;
    const int m0 = blockIdx.x * 128, n0 = blockIdx.y * 128;
    const int srow = (l >> 3) & 7, pch = l & 7;
    const int cch = pch ^ srow;
    const u16* ga[4]; const u16* gb[4];
#pragma unroll
    for (int r = 0; r < 4; ++r) {
        int seg = r * 4 + w;
        ga[r] = A + (i64)(m0 + seg * 8 + srow) * K + cch * 8;
        gb[r] = B + (i64)(n0 + seg * 8 + srow) * K + cch * 8;
    }
    f32x4 acc[4][4] = {};
    const int lr = l & 15, lg = l >> 4;
    const int wm = (w >> 1) * 64, wn = (w & 1) * 64;
    for (int kk = 0; kk < K; kk += 64) {
#pragma unroll
        for (int r = 0; r < 4; ++r) { GLOAD16(ga[r], smA + (r * 4 + w) * 512); ga[r] += 64; }
#pragma unroll
        for (int r = 0; r < 4; ++r) { GLOAD16(gb[r], smB + (r * 4 + w) * 512); gb[r] += 64; }
        __syncthreads();
#pragma unroll
        for (int s = 0; s < 2; ++s) {
            const int ph = ((s * 4 + lg) ^ (lr & 7)) * 8;
            bf16x8 av[4], bv[4];
#pragma unroll
            for (int i = 0; i < 4; ++i)
                av[i] = *(const bf16x8*)(smA + (wm + i * 16 + lr) * 64 + ph);
#pragma unroll
            for (int j = 0; j < 4; ++j)
                bv[j] = *(const bf16x8*)(smB + (wn + j * 16 + lr) * 64 + ph);
#pragma unroll
            for (int i = 0; i < 4; ++i)
#pragma unroll
                for (int j = 0; j < 4; ++j)
                    acc[i][j] = __builtin_amdgcn_mfma_f32_16x16x32_bf16(av[i], bv[j], acc[i][j], 0, 0, 0);
        }
        __syncthreads();
    }
#pragma unroll
    for (int i = 0; i < 4; ++i) {
        int mbase = m0 + wm + i * 16 + 4 * lg;
#pragma unroll
        for (int j = 0; j < 4; ++j) {
            int c = n0 + wn + j * 16 + lr;
            if (MODE == 3) {
                int NCT = dgate >> 4;
                int T = (m0 + wm + 16 * i) >> 4;
                int Cg = n0 + wn + 16 * j;
                int g = Cg / dgate;
                int ct = (Cg % dgate) >> 4;
                float bs = bias[c];
                u32 d0 = (u32)f2bf(acc[i][j][0] + bs) | ((u32)f2bf(acc[i][j][1] + bs) << 16);
                u32 d1 = (u32)f2bf(acc[i][j][2] + bs) | ((u32)f2bf(acc[i][j][3] + bs) << 16);
                ((uint2*)Cp)[((i64)(T * NCT + ct) * 3 + g) * 64 + l] = make_uint2(d0, d1);
            } else {
                if (c >= Nstore) continue;
                float bs = bias[c];
#pragma unroll
                for (int r = 0; r < 4; ++r) {
                    int mm = mbase + r;
                    if (mm < Mstore) {
                        float v = acc[i][j][r] + bs;
                        if (MODE == 2) v = fmaxf(v, 0.f);
                        if (MODE == 0) ((float*)Cp)[(i64)mm * ldc + c] = v;
                        else           ((u16*)Cp)[(i64)mm * ldc + c] = f2bf(v);
                    }
                }
            }
        }
    }
}

// ---------------------------------------- decoder: fused gh-GEMM + GRU pointwise
template<int S>
__global__ __launch_bounds__(256) void gru_fused(const u16* __restrict__ Abf,
                                                 const u16* __restrict__ Whh,
                                                 const float* __restrict__ bhh,
                                                 const u16* __restrict__ gi,
                                                 float* __restrict__ h,
                                                 u16* __restrict__ hbf,
                                                 u16* __restrict__ hy, int d) {
    __shared__ u16 smA[128 * 64];
    __shared__ u16 smB[3 * 64 * 64];
    const int tid = threadIdx.x;
    const int w = tid >> 6, l = tid & 63;
    const int m0 = blockIdx.x * 128;
    const int c0 = blockIdx.y * 64;
    const int srow = (l >> 3) & 7, pch = l & 7;
    const int cch = pch ^ srow;
    const u16* ga[4]; const u16* gb[6];
#pragma unroll
    for (int r = 0; r < 4; ++r)
        ga[r] = Abf + (i64)(m0 + (r * 4 + w) * 8 + srow) * d + cch * 8;
#pragma unroll
    for (int q = 0; q < 6; ++q) {
        int gs = q * 4 + w;
        int g = gs >> 3, sp = gs & 7;
        gb[q] = Whh + (i64)(g * d + c0 + sp * 8 + srow) * d + cch * 8;
    }
    f32x4 acc[3][4][2] = {};
    const int lr = l & 15, lg = l >> 4;
    const int wm = (w >> 1) * 64, wc = (w & 1) * 32;
    for (int kk = 0; kk < d; kk += 64) {
#pragma unroll
        for (int r = 0; r < 4; ++r) { GLOAD16(ga[r], smA + (r * 4 + w) * 512); ga[r] += 64; }
#pragma unroll
        for (int q = 0; q < 6; ++q) { GLOAD16(gb[q], smB + (q * 4 + w) * 512); gb[q] += 64; }
        __syncthreads();
#pragma unroll
        for (int s = 0; s < 2; ++s) {
            const int ph = ((s * 4 + lg) ^ (lr & 7)) * 8;
            bf16x8 av[4], bv[3][2];
#pragma unroll
            for (int i = 0; i < 4; ++i)
                av[i] = *(const bf16x8*)(smA + (wm + i * 16 + lr) * 64 + ph);
#pragma unroll
            for (int g = 0; g < 3; ++g)
#pragma unroll
                for (int j = 0; j < 2; ++j)
                    bv[g][j] = *(const bf16x8*)(smB + g * 4096 + (wc + j * 16 + lr) * 64 + ph);
#pragma unroll
            for (int g = 0; g < 3; ++g)
#pragma unroll
                for (int i = 0; i < 4; ++i)
#pragma unroll
                    for (int j = 0; j < 2; ++j)
                        acc[g][i][j] = __builtin_amdgcn_mfma_f32_16x16x32_bf16(av[i], bv[g][j], acc[g][i][j], 0, 0, 0);
        }
        __syncthreads();
    }
#pragma unroll
    for (int i = 0; i < 4; ++i) {
        int mbase = m0 + wm + i * 16 + 4 * lg;
#pragma unroll
        for (int j = 0; j < 2; ++j) {
            int cc = c0 + wc + j * 16 + lr;
            float b0 = bhh[cc], b1 = bhh[d + cc], b2 = bhh[2 * d + cc];
#pragma unroll
            for (int r = 0; r < 4; ++r) {
                int mm = mbase + r;
                if (mm >= NB) continue;
                float hr = acc[0][i][j][r] + b0;
                float hz = acc[1][i][j][r] + b1;
                float hn = acc[2][i][j][r] + b2;
                int e = mm % ENC_;
                float ho = h[(i64)mm * d + cc];
#pragma unroll
                for (int sy = 0; sy < S; ++sy) {
                    i64 gib = (i64)(e * S + sy) * 3 * d + cc;
                    float rr = sigf(bf2f(gi[gib]) + hr);
                    float zz = sigf(bf2f(gi[gib + d]) + hz);
                    float nn = tanhfast(bf2f(gi[gib + 2 * d]) + rr * hn);
                    float v = (1.f - zz) * nn + zz * ho;
                    hy[((i64)mm * S + sy) * d + cc] = f2bf(v);
                }
            }
        }
    }
}

// ---------------------------------------- persistent GRU chain (reg-resident h)
// Block owns 64 rows. cg loop FULLY UNROLLED -> hm/ha constant-indexed (VGPRs).
template<int D>
__global__ __launch_bounds__(256, 1) void gru_chain(const u16* __restrict__ whh_perm,
                                                    const float* __restrict__ bhh,
                                                    const u16* __restrict__ gi,
                                                    i64 gi_step_stride, int gi_mod,
                                                    float* __restrict__ hglob,
                                                    u16* __restrict__ hbf,
                                                    int t0, int nsteps) {
    constexpr int NCT = D / 16;
    constexpr int KT = D / 32;
    constexpr int NCG = D / 32;
    constexpr int NCHUNK = NCG * 3;
    constexpr int CPW = D / 64;
    __shared__ __align__(16) u16 lds[2 * 32 * D];

    const int tid = threadIdx.x, w = tid >> 6, l = tid & 63;
    const int q = l >> 4, lr = l & 15;
    const int blk = blockIdx.x;
    const int m_wave = blk * 64 + w * 16;
    const int T = blk * 4 + w;

    float hm[NCT][4];
    bf16x8 ha[KT];
    uint4 ld[CPW];

    auto exchange = [&]() {
        __syncthreads();
#pragma unroll
        for (int nt = 0; nt < NCT; ++nt)
#pragma unroll
            for (int r = 0; r < 4; ++r) {
                int row = w * 16 + 4 * q + r;
                int pg = (2 * nt + (lr >> 3)) ^ ((4 * q + r) & 7);
                lds[row * D + pg * 8 + (lr & 7)] = f2bf(hm[nt][r]);
            }
        __syncthreads();
#pragma unroll
        for (int kt = 0; kt < KT; ++kt)
            ha[kt] = *(const bf16x8*)&lds[(w * 16 + lr) * D + (((4 * kt + q) ^ (lr & 7)) << 3)];
        __syncthreads();
    };

    if (t0 == 0) {
#pragma unroll
        for (int nt = 0; nt < NCT; ++nt)
#pragma unroll
            for (int r = 0; r < 4; ++r) hm[nt][r] = 0.f;
#pragma unroll
        for (int kt = 0; kt < KT; ++kt)
#pragma unroll
            for (int e = 0; e < 8; ++e) ha[kt][e] = 0;
    } else {
#pragma unroll
        for (int nt = 0; nt < NCT; ++nt)
#pragma unroll
            for (int r = 0; r < 4; ++r)
                hm[nt][r] = hglob[(i64)(m_wave + 4 * q + r) * D + nt * 16 + lr];
        exchange();
    }

    auto load_chunk = [&](int ci) {
#pragma unroll
        for (int i = 0; i < CPW; ++i)
            ld[i] = *(const uint4*)&whh_perm[(i64)ci * 32 * D + ((w * CPW + i) * 64 + l) * 8];
    };
    auto write_chunk = [&](int p) {
#pragma unroll
        for (int i = 0; i < CPW; ++i)
            *(uint4*)&lds[p * 32 * D + ((w * CPW + i) * 64 + l) * 8] = ld[i];
    };
    auto mfma_chunk = [&](int ci, f32x4& c0, f32x4& c1) {
        const int bufb = (ci & 1) * 32 * D;
        c0 = f32x4{0.f, 0.f, 0.f, 0.f};
        c1 = f32x4{0.f, 0.f, 0.f, 0.f};
#pragma unroll
        for (int kt = 0; kt < KT; ++kt) {
            int pg = ((4 * kt + q) ^ (lr & 7)) << 3;
            bf16x8 b0 = *(const bf16x8*)&lds[bufb + lr * D + pg];
            bf16x8 b1 = *(const bf16x8*)&lds[bufb + (16 + lr) * D + pg];
            c0 = __builtin_amdgcn_mfma_f32_16x16x32_bf16(ha[kt], b0, c0, 0, 0, 0);
            c1 = __builtin_amdgcn_mfma_f32_16x16x32_bf16(ha[kt], b1, c1, 0, 0, 0);
        }
    };

#pragma unroll 1
    for (int t = 0; t < nsteps; ++t) {
        const u16* git = gi + (i64)(gi_mod ? ((t0 + t) % gi_mod) : t) * gi_step_stride;
        load_chunk(0);
        write_chunk(0);
        __syncthreads();
#pragma unroll
        for (int cg = 0; cg < NCG; ++cg) {
            f32x4 aR0, aR1, aZ0, aZ1, aN0, aN1;
            uint2 gipre[2][3];
            const int ci = cg * 3;
            if (ci + 1 < NCHUNK) load_chunk(ci + 1);
#pragma unroll
            for (int j = 0; j < 2; ++j)
#pragma unroll
                for (int g = 0; g < 3; ++g)
                    gipre[j][g] = *(const uint2*)&git[(((i64)(T * NCT + cg * 2 + j) * 3 + g) * 64 + l) * 4];
            mfma_chunk(ci, aR0, aR1);
            if (ci + 1 < NCHUNK) { write_chunk((ci + 1) & 1); __syncthreads(); }
            if (ci + 2 < NCHUNK) load_chunk(ci + 2);
            mfma_chunk(ci + 1, aZ0, aZ1);
            if (ci + 2 < NCHUNK) { write_chunk((ci + 2) & 1); __syncthreads(); }
            if (ci + 3 < NCHUNK) load_chunk(ci + 3);
            mfma_chunk(ci + 2, aN0, aN1);
#pragma unroll
            for (int j = 0; j < 2; ++j) {
                int cc = cg * 32 + j * 16 + lr;
                float b0 = bhh[cc], b1 = bhh[D + cc], b2 = bhh[2 * D + cc];
                const f32x4& gr = j ? aR1 : aR0;
                const f32x4& gz = j ? aZ1 : aZ0;
                const f32x4& gn = j ? aN1 : aN0;
#pragma unroll
                for (int r = 0; r < 4; ++r) {
                    float rr = sigf(bsel(gipre[j][0], r) + gr[r] + b0);
                    float zz = sigf(bsel(gipre[j][1], r) + gz[r] + b1);
                    float nn = tanhfast(bsel(gipre[j][2], r) + rr * (gn[r] + b2));
                    hm[cg * 2 + j][r] = (1.f - zz) * nn + zz * hm[cg * 2 + j][r];
                }
            }
            if (ci + 3 < NCHUNK) { write_chunk((ci + 3) & 1); __syncthreads(); }
        }
        exchange();
    }
#pragma unroll
    for (int nt = 0; nt < NCT; ++nt)
#pragma unroll
        for (int r = 0; r < 4; ++r) {
            i64 o = (i64)(m_wave + 4 * q + r) * D + nt * 16 + lr;
            hglob[o] = hm[nt][r];
            hbf[o] = f2bf(hm[nt][r]);
        }
}

// ---------------------------------------------------------------- host
extern "C" void kernel_launch(void* const* d_in, const int* in_sizes, int n_in,
                              void* d_out, int out_size, void* d_ws, size_t ws_size,
                              hipStream_t stream) {
    const float* x      = (const float*)d_in[0];
    const float* W_emb0 = (const float*)d_in[1];
    const float* b_emb0 = (const float*)d_in[2];
    const float* Wih0   = (const float*)d_in[3];
    const float* Whh0   = (const float*)d_in[4];
    const float* bih0   = (const float*)d_in[5];
    const float* bhh0   = (const float*)d_in[6];
    const float* Wpred0 = (const float*)d_in[7];
    const float* bpred0 = (const float*)d_in[8];
    const float* pos0   = (const float*)d_in[9];
    const float* chan0  = (const float*)d_in[10];
    const float* W_emb1 = (const float*)d_in[11];
    const float* b_emb1 = (const float*)d_in[12];
    const float* Wih1   = (const float*)d_in[13];
    const float* Whh1   = (const float*)d_in[14];
    const float* bih1   = (const float*)d_in[15];
    const float* bhh1   = (const float*)d_in[16];
    const float* Wpred1 = (const float*)d_in[17];
    const float* bpred1 = (const float*)d_in[18];
    const float* pos1   = (const float*)d_in[19];
    const float* chan1  = (const float*)d_in[20];
    float* out = (float*)d_out;

    i64 off = 0;
    char* base = (char*)d_ws;
    auto alloc = [&](i64 bytes) -> void* {
        void* p = base + off; off += (bytes + 255) & ~(i64)255; return p;
    };
    float* f_h    = (float*)alloc((i64)MP * 512 * 4);
    u16*   f_hbf  = (u16*)  alloc((i64)MP * 512 * 2);
    u16*   whh0p  = (u16*)  alloc((i64)1536 * 512 * 2);
    u16*   whh1p  = (u16*)  alloc((i64)768 * 256 * 2);
    u16*   wih0b  = (u16*)  alloc((i64)1536 * 512 * 2);
    u16*   whh0b  = (u16*)  alloc((i64)1536 * 512 * 2);
    u16*   wih1b  = (u16*)  alloc((i64)768 * 256 * 2);
    u16*   whh1b  = (u16*)  alloc((i64)768 * 256 * 2);
    u16*   we0b   = (u16*)  alloc((i64)512 * 64 * 2);
    u16*   we1b   = (u16*)  alloc((i64)256 * 64 * 2);
    u16*   wp0b   = (u16*)  alloc((i64)128 * 512 * 2);
    u16*   wp1b   = (u16*)  alloc((i64)128 * 256 * 2);
    u16*   f_pm0  = (u16*)  alloc((i64)768 * 512 * 2);
    u16*   f_pm1  = (u16*)  alloc((i64)1408 * 256 * 2);
    u16*   f_gidec= (u16*)  alloc((i64)768 * 1536 * 2);
    float* f_y0   = (float*)alloc((i64)NB * 96 * 4);
    float* f_y1   = (float*)alloc((i64)NB * 96 * 4);
    i64 fixed = off;

    char* R = base + fixed;
    i64 a1 = (((i64)4 * MP * 64 * 2) + 255) & ~(i64)255;
    i64 a2 = (((i64)4 * MP * 256 * 2) + 255) & ~(i64)255;
    i64 a3 = (i64)4 * MP * 768 * 2;
    i64 R1 = a1 + a2 + a3;
    u16* f_seg1 = (u16*)R;
    u16* f_xe1  = (u16*)(R + a1);
    u16* f_gi1  = (u16*)(R + a1 + a2);
    u16* f_hy   = f_gi1;
    int gsz = 2;
    {
        const int cand[3] = {15, 5, 3};
        for (int ii = 0; ii < 3; ++ii) {
            i64 need = (i64)cand[ii] * MP * (64 + 512 + 1536) * 2 + 3 * 256;
            i64 tot = fixed + (need > R1 ? need : R1);
            if (tot <= (i64)ws_size) { gsz = cand[ii]; break; }
        }
    }
    u16* f_seg0 = (u16*)R;
    i64 s1 = (((i64)gsz * MP * 64 * 2) + 255) & ~(i64)255;
    i64 s2 = (((i64)gsz * MP * 512 * 2) + 255) & ~(i64)255;
    u16* f_xe0 = (u16*)(R + s1);
    u16* f_gi0 = (u16*)(R + s1 + s2);

    auto cvt = [&](const float* s, u16* dst, int Rr, int C, int Rp, int Cp) {
        i64 tot = (i64)Rp * Cp;
        convert_pad<<<(int)((tot + 255) / 256), 256, 0, stream>>>(s, dst, Rr, C, Rp, Cp);
    };
    auto gemmN = [&](const u16* A, const u16* B, const float* bias, void* C,
                     int gx, int Nc, int K, int Mstore, int ldc, int mode, int dgate) {
        dim3 g(gx, (Nc + 127) / 128);
        if (mode == 0)      gemm_bf16mfma<0><<<g, 256, 0, stream>>>(A, B, bias, C, K, Mstore, Nc, ldc, dgate);
        else if (mode == 1) gemm_bf16mfma<1><<<g, 256, 0, stream>>>(A, B, bias, C, K, Mstore, Nc, ldc, dgate);
        else if (mode == 2) gemm_bf16mfma<2><<<g, 256, 0, stream>>>(A, B, bias, C, K, Mstore, Nc, ldc, dgate);
        else                gemm_bf16mfma<3><<<g, 256, 0, stream>>>(A, B, bias, C, K, Mstore, Nc, ldc, dgate);
    };

    cvt(Wih0, wih0b, 1536, 512, 1536, 512);
    cvt(Whh0, whh0b, 1536, 512, 1536, 512);
    cvt(Wih1, wih1b, 768, 256, 768, 256);
    cvt(Whh1, whh1b, 768, 256, 768, 256);
    cvt(W_emb0, we0b, 512, 48, 512, 64);
    cvt(W_emb1, we1b, 256, 24, 256, 64);
    cvt(Wpred0, wp0b, 48, 512, 128, 512);
    cvt(Wpred1, wp1b, 24, 256, 128, 256);
    convert_whh_perm<<<(int)(((i64)3 * 512 * 512 + 255) / 256), 256, 0, stream>>>(Whh0, whh0p, 512);
    convert_whh_perm<<<(int)(((i64)3 * 256 * 256 + 255) / 256), 256, 0, stream>>>(Whh1, whh1p, 256);
    pmat_fill_bf<<<(int)(((i64)768 * 512 + 255) / 256), 256, 0, stream>>>(pos0, chan0, f_pm0, 2, 512, 768);
    pmat_fill_bf<<<(int)(((i64)1408 * 256 + 255) / 256), 256, 0, stream>>>(pos1, chan1, f_pm1, 4, 256, 1408);

    // ================= layer 0: d=512, s=48, 15 steps in groups of gsz ========
    for (int t0 = 0; t0 < 15;) {
        int g = 15 - t0 < gsz ? 15 - t0 : gsz;
        i64 tot = (i64)g * MP * 64;
        seg_gather_bf<<<(int)((tot + 255) / 256), 256, 0, stream>>>(x, f_seg0, t0, g, 48, 64);
        gemmN(f_seg0, we0b, b_emb0, f_xe0, g * 81, 512, 64, g * MP, 512, 2, 0);
        gemmN(f_xe0, wih0b, bih0, f_gi0, g * 81, 1536, 512, 0, 0, 3, 512);
        gru_chain<512><<<162, 256, 0, stream>>>(whh0p, bhh0, f_gi0, (i64)MP * 1536, 0,
                                                f_h, f_hbf, t0, g);
        t0 += g;
    }
    // decoder 0
    gemmN(f_pm0, wih0b, bih0, f_gidec, 6, 1536, 512, 642, 1536, 1, 0);
    gru_fused<2><<<dim3(81, 8), 256, 0, stream>>>(f_hbf, whh0b, bhh0, f_gidec,
                                                  f_h, nullptr, f_hy, 512);
    gemmN(f_hy, wp0b, bpred0, f_y0, 161, 48, 512, 2 * NB, 48, 0, 0);

    // ================= layer 1: d=256, s=24, 60 steps (4 gi segments) =========
    {
        i64 tot = (i64)4 * MP * 64;
        seg_gather_bf<<<(int)((tot + 255) / 256), 256, 0, stream>>>(x, f_seg1, 0, 4, 24, 64);
    }
    gemmN(f_seg1, we1b, b_emb1, f_xe1, 324, 256, 64, 4 * MP, 256, 2, 0);
    gemmN(f_xe1, wih1b, bih1, f_gi1, 324, 768, 256, 0, 0, 3, 256);
    gru_chain<256><<<162, 256, 0, stream>>>(whh1p, bhh1, f_gi1, (i64)MP * 768, 4,
                                            f_h, f_hbf, 0, 60);
    // decoder 1
    gemmN(f_pm1, wih1b, bih1, f_gidec, 11, 768, 256, 1284, 768, 1, 0);
    gru_fused<4><<<dim3(81, 4), 256, 0, stream>>>(f_hbf, whh1b, bhh1, f_gidec,
                                                  f_h, nullptr, f_hy, 256);
    gemmN(f_hy, wp1b, bpred1, f_y1, 321, 24, 256, 4 * NB, 24, 0, 0);

    // ================= combine =================
    out_kernel<<<(BATCH_ * PRED_ * ENC_ + 255) / 256, 256, 0, stream>>>(x, f_y0, f_y1, out);
}

// Round 5
// 3138.370 us; speedup vs baseline: 2.5651x; 2.5651x over previous
//
#include <hip/hip_runtime.h>
#include <math.h>

// Hierarchical RNN — round 5: per-step fused gh-GEMM+GRU with COALESCED
// epilogue (gi in MFMA-fragment-packed layout, h fp32 master in fragment
// layout + bf16 row-major mirror). Persistent-chain approach dropped
// (R3/R4: latency-bound at 1 block/CU, ~50us/step).
// N = B*ENC = 10272 rows padded to MP = 10368 = 81*128.

#define NB     10272
#define MP     10368
#define ENC_   321
#define SEQ_   720
#define PRED_  96
#define BATCH_ 32

typedef long long i64;
typedef unsigned short u16;
typedef unsigned int u32;
using bf16x8 = __attribute__((ext_vector_type(8))) short;
using f32x4  = __attribute__((ext_vector_type(4))) float;

#define AS1 __attribute__((address_space(1)))
#define AS3 __attribute__((address_space(3)))
#define GLOAD16(g, l) __builtin_amdgcn_global_load_lds((const AS1 void*)(g), (AS3 void*)(l), 16, 0, 0)

__device__ __forceinline__ float bf2f(u16 u) {
    union { u32 i; float f; } v; v.i = ((u32)u) << 16; return v.f;
}
__device__ __forceinline__ u16 f2bf(float f) {
    union { float f; u32 i; } v; v.f = f;
    return (u16)((v.i + 0x7fff + ((v.i >> 16) & 1)) >> 16);
}
__device__ __forceinline__ float sigf(float x) {
    x = fminf(fmaxf(x, -30.f), 30.f);
    return 1.f / (1.f + __expf(-x));
}
__device__ __forceinline__ float tanhfast(float x) {
    x = fminf(fmaxf(x, -15.f), 15.f);
    float e = __expf(2.f * x);
    return (e - 1.f) / (e + 1.f);
}
__device__ __forceinline__ float bsel(uint2 u, int r) {
    u32 wv = (r & 2) ? u.y : u.x;
    return bf2f((u16)((r & 1) ? (wv >> 16) : (wv & 0xffff)));
}

// ---------------------------------------------------------------- small utils
__global__ __launch_bounds__(256) void zero2_kernel(float* __restrict__ a,
                                                    u16* __restrict__ b, i64 n) {
    i64 i = (i64)blockIdx.x * 256 + threadIdx.x;
    if (i < n) { a[i] = 0.f; b[i] = 0; }
}

__global__ __launch_bounds__(256) void convert_pad(const float* __restrict__ src,
                                                   u16* __restrict__ dst,
                                                   int R, int C, int Rp, int Cp) {
    i64 idx = (i64)blockIdx.x * 256 + threadIdx.x;
    i64 total = (i64)Rp * Cp;
    if (idx >= total) return;
    int r = (int)(idx / Cp);
    int c = (int)(idx - (i64)r * Cp);
    dst[idx] = (r < R && c < C) ? f2bf(src[(i64)r * C + c]) : (u16)0;
}

__global__ __launch_bounds__(256) void seg_gather_bf(const float* __restrict__ x,
                                                     u16* __restrict__ dst,
                                                     int t0, int T, int s, int Kp) {
    i64 idx = (i64)blockIdx.x * 256 + threadIdx.x;
    i64 per_t = (i64)MP * Kp;
    i64 total = (i64)T * per_t;
    if (idx >= total) return;
    int t = (int)(idx / per_t);
    i64 rem = idx - (i64)t * per_t;
    int j = (int)(rem / MP);
    int n = (int)(rem - (i64)j * MP);
    float v = 0.f;
    if (n < NB && j < s) {
        int b = n / ENC_, e = n - b * ENC_;
        const float* xb = x + (i64)b * SEQ_ * ENC_ + e;
        v = xb[(i64)((t0 + t) * s + j) * ENC_] - xb[(i64)(SEQ_ - 1) * ENC_];
    }
    dst[((i64)t * MP + n) * Kp + j] = f2bf(v);
}

__global__ __launch_bounds__(256) void pmat_fill_bf(const float* __restrict__ pos,
                                                    const float* __restrict__ chan,
                                                    u16* __restrict__ dst,
                                                    int S, int d, int Rp) {
    i64 idx = (i64)blockIdx.x * 256 + threadIdx.x;
    i64 total = (i64)Rp * d;
    if (idx >= total) return;
    int row = (int)(idx / d);
    int c = (int)(idx - (i64)row * d);
    float v = 0.f;
    if (row < ENC_ * S) {
        int e = row / S, sy = row - e * S;
        int half = d >> 1;
        v = (c < half) ? pos[sy * half + c] : chan[e * half + (c - half)];
    }
    dst[idx] = f2bf(v);
}

__global__ __launch_bounds__(256) void out_kernel(const float* __restrict__ x,
                                                  const float* __restrict__ y0,
                                                  const float* __restrict__ y1,
                                                  float* __restrict__ out) {
    int idx = blockIdx.x * 256 + threadIdx.x;
    const int total = BATCH_ * PRED_ * ENC_;
    if (idx >= total) return;
    int b = idx / (PRED_ * ENC_);
    int r = idx - b * (PRED_ * ENC_);
    int p = r / ENC_;
    int e = r - p * ENC_;
    int n = b * ENC_ + e;
    float sl = x[(i64)b * SEQ_ * ENC_ + (i64)(SEQ_ - 1) * ENC_ + e];
    out[idx] = sl + 0.5f * (y0[(i64)n * PRED_ + p] + y1[(i64)n * PRED_ + p]);
}

// ------------------------------------------------- bf16 MFMA NT GEMM 128x128xK
// MODE: 0 fp32 natural, 1 bf16 natural, 2 bf16+relu, 3 fragment-packed
// (per 16x16 tile: uint2/lane = bf16 r0..r3, tiles indexed [(T*NCT+ct)*3+g])
template<int MODE>
__global__ __launch_bounds__(256) void gemm_bf16mfma(const u16* __restrict__ A,
                                                     const u16* __restrict__ B,
                                                     const float* __restrict__ bias,
                                                     void* __restrict__ Cp,
                                                     int K, int Mstore, int Nstore,
                                                     int ldc, int dgate) {
    __shared__ u16 smA[128 * 64];
    __shared__ u16 smB[128 * 64];
    const int tid = threadIdx.x;
    const int w = tid >> 6, l = tid & 63;
    const int m0 = blockIdx.x * 128, n0 = blockIdx.y * 128;
    const int srow = (l >> 3) & 7, pch = l & 7;
    const int cch = pch ^ srow;
    const u16* ga[4]; const u16* gb[4];
#pragma unroll
    for (int r = 0; r < 4; ++r) {
        int seg = r * 4 + w;
        ga[r] = A + (i64)(m0 + seg * 8 + srow) * K + cch * 8;
        gb[r] = B + (i64)(n0 + seg * 8 + srow) * K + cch * 8;
    }
    f32x4 acc[4][4] = {};
    const int lr = l & 15, lg = l >> 4;
    const int wm = (w >> 1) * 64, wn = (w & 1) * 64;
    for (int kk = 0; kk < K; kk += 64) {
#pragma unroll
        for (int r = 0; r < 4; ++r) { GLOAD16(ga[r], smA + (r * 4 + w) * 512); ga[r] += 64; }
#pragma unroll
        for (int r = 0; r < 4; ++r) { GLOAD16(gb[r], smB + (r * 4 + w) * 512); gb[r] += 64; }
        __syncthreads();
#pragma unroll
        for (int s = 0; s < 2; ++s) {
            const int ph = ((s * 4 + lg) ^ (lr & 7)) * 8;
            bf16x8 av[4], bv[4];
#pragma unroll
            for (int i = 0; i < 4; ++i)
                av[i] = *(const bf16x8*)(smA + (wm + i * 16 + lr) * 64 + ph);
#pragma unroll
            for (int j = 0; j < 4; ++j)
                bv[j] = *(const bf16x8*)(smB + (wn + j * 16 + lr) * 64 + ph);
#pragma unroll
            for (int i = 0; i < 4; ++i)
#pragma unroll
                for (int j = 0; j < 4; ++j)
                    acc[i][j] = __builtin_amdgcn_mfma_f32_16x16x32_bf16(av[i], bv[j], acc[i][j], 0, 0, 0);
        }
        __syncthreads();
    }
#pragma unroll
    for (int i = 0; i < 4; ++i) {
        int mbase = m0 + wm + i * 16 + 4 * lg;
#pragma unroll
        for (int j = 0; j < 4; ++j) {
            int c = n0 + wn + j * 16 + lr;
            if (MODE == 3) {
                int NCT = dgate >> 4;
                int T = (m0 + wm + 16 * i) >> 4;
                int Cg = n0 + wn + 16 * j;
                int g = Cg / dgate;
                int ct = (Cg % dgate) >> 4;
                float bs = bias[c];
                u32 d0 = (u32)f2bf(acc[i][j][0] + bs) | ((u32)f2bf(acc[i][j][1] + bs) << 16);
                u32 d1 = (u32)f2bf(acc[i][j][2] + bs) | ((u32)f2bf(acc[i][j][3] + bs) << 16);
                ((uint2*)Cp)[((i64)(T * NCT + ct) * 3 + g) * 64 + l] = make_uint2(d0, d1);
            } else {
                if (c >= Nstore) continue;
                float bs = bias[c];
#pragma unroll
                for (int r = 0; r < 4; ++r) {
                    int mm = mbase + r;
                    if (mm < Mstore) {
                        float v = acc[i][j][r] + bs;
                        if (MODE == 2) v = fmaxf(v, 0.f);
                        if (MODE == 0) ((float*)Cp)[(i64)mm * ldc + c] = v;
                        else           ((u16*)Cp)[(i64)mm * ldc + c] = f2bf(v);
                    }
                }
            }
        }
    }
}

// --------------------------- fused gh-GEMM + GRU pointwise, v2 (coalesced)
// S==0 encoder: gi fragment-packed (uint2/lane/tile/gate), h fp32 master in
//   fragment layout (f32x4/lane/tile) updated in place + bf16 row-major mirror.
// S>0 decoder: gi_dec natural [row 3D] (small, L2-hot), h_old from fragment
//   master, writes hy bf16 row-major.
template<int D, int S>
__global__ __launch_bounds__(256) void gru_fused_v2(const u16* __restrict__ Abf,
                                                    const u16* __restrict__ Whh,
                                                    const float* __restrict__ bhh,
                                                    const u16* __restrict__ gi,
                                                    f32x4* __restrict__ hfrag,
                                                    u16* __restrict__ hbf,
                                                    u16* __restrict__ hy) {
    constexpr int NCT = D / 16;
    __shared__ u16 smA[128 * 64];
    __shared__ u16 smB[3 * 64 * 64];
    const int tid = threadIdx.x;
    const int w = tid >> 6, l = tid & 63;
    const int m0 = blockIdx.x * 128;
    const int c0 = blockIdx.y * 64;
    const int srow = (l >> 3) & 7, pch = l & 7;
    const int cch = pch ^ srow;
    const u16* ga[4]; const u16* gb[6];
#pragma unroll
    for (int r = 0; r < 4; ++r)
        ga[r] = Abf + (i64)(m0 + (r * 4 + w) * 8 + srow) * D + cch * 8;
#pragma unroll
    for (int q = 0; q < 6; ++q) {
        int gs = q * 4 + w;
        int g = gs >> 3, sp = gs & 7;
        gb[q] = Whh + (i64)(g * D + c0 + sp * 8 + srow) * D + cch * 8;
    }
    f32x4 acc[3][4][2] = {};
    const int lr = l & 15, lg = l >> 4;
    const int wm = (w >> 1) * 64, wc = (w & 1) * 32;
    for (int kk = 0; kk < D; kk += 64) {
#pragma unroll
        for (int r = 0; r < 4; ++r) { GLOAD16(ga[r], smA + (r * 4 + w) * 512); ga[r] += 64; }
#pragma unroll
        for (int q = 0; q < 6; ++q) { GLOAD16(gb[q], smB + (q * 4 + w) * 512); gb[q] += 64; }
        __syncthreads();
#pragma unroll
        for (int s = 0; s < 2; ++s) {
            const int ph = ((s * 4 + lg) ^ (lr & 7)) * 8;
            bf16x8 av[4], bv[3][2];
#pragma unroll
            for (int i = 0; i < 4; ++i)
                av[i] = *(const bf16x8*)(smA + (wm + i * 16 + lr) * 64 + ph);
#pragma unroll
            for (int g = 0; g < 3; ++g)
#pragma unroll
                for (int j = 0; j < 2; ++j)
                    bv[g][j] = *(const bf16x8*)(smB + g * 4096 + (wc + j * 16 + lr) * 64 + ph);
#pragma unroll
            for (int g = 0; g < 3; ++g)
#pragma unroll
                for (int i = 0; i < 4; ++i)
#pragma unroll
                    for (int j = 0; j < 2; ++j)
                        acc[g][i][j] = __builtin_amdgcn_mfma_f32_16x16x32_bf16(av[i], bv[g][j], acc[g][i][j], 0, 0, 0);
        }
        __syncthreads();
    }
#pragma unroll
    for (int i = 0; i < 4; ++i) {
        const int Trow = (m0 + wm + 16 * i) >> 4;
        const int rowb = m0 + wm + 16 * i + 4 * lg;
#pragma unroll
        for (int j = 0; j < 2; ++j) {
            const int cc = c0 + wc + 16 * j + lr;
            const int ct = (c0 + wc + 16 * j) >> 4;
            const i64 tb = (i64)Trow * NCT + ct;
            float b0 = bhh[cc], b1 = bhh[D + cc], b2 = bhh[2 * D + cc];
            f32x4 ho = hfrag[tb * 64 + l];
            if constexpr (S == 0) {
                uint2 g0 = ((const uint2*)gi)[(tb * 3 + 0) * 64 + l];
                uint2 g1 = ((const uint2*)gi)[(tb * 3 + 1) * 64 + l];
                uint2 g2 = ((const uint2*)gi)[(tb * 3 + 2) * 64 + l];
                f32x4 hn_;
#pragma unroll
                for (int r = 0; r < 4; ++r) {
                    float rr = sigf(bsel(g0, r) + acc[0][i][j][r] + b0);
                    float zz = sigf(bsel(g1, r) + acc[1][i][j][r] + b1);
                    float nn = tanhfast(bsel(g2, r) + rr * (acc[2][i][j][r] + b2));
                    hn_[r] = (1.f - zz) * nn + zz * ho[r];
                }
                hfrag[tb * 64 + l] = hn_;
#pragma unroll
                for (int r = 0; r < 4; ++r)
                    hbf[(i64)(rowb + r) * D + cc] = f2bf(hn_[r]);
            } else {
#pragma unroll
                for (int r = 0; r < 4; ++r) {
                    int mm = rowb + r;
                    if (mm >= NB) continue;
                    int e = mm % ENC_;
                    float hr = acc[0][i][j][r] + b0;
                    float hz = acc[1][i][j][r] + b1;
                    float hn2 = acc[2][i][j][r] + b2;
#pragma unroll
                    for (int sy = 0; sy < S; ++sy) {
                        i64 gib = (i64)(e * S + sy) * 3 * D + cc;
                        float rr = sigf(bf2f(gi[gib]) + hr);
                        float zz = sigf(bf2f(gi[gib + D]) + hz);
                        float nn = tanhfast(bf2f(gi[gib + 2 * D]) + rr * hn2);
                        hy[((i64)mm * S + sy) * D + cc] = f2bf((1.f - zz) * nn + zz * ho[r]);
                    }
                }
            }
        }
    }
}

// ---------------------------------------------------------------- host
extern "C" void kernel_launch(void* const* d_in, const int* in_sizes, int n_in,
                              void* d_out, int out_size, void* d_ws, size_t ws_size,
                              hipStream_t stream) {
    const float* x      = (const float*)d_in[0];
    const float* W_emb0 = (const float*)d_in[1];
    const float* b_emb0 = (const float*)d_in[2];
    const float* Wih0   = (const float*)d_in[3];
    const float* Whh0   = (const float*)d_in[4];
    const float* bih0   = (const float*)d_in[5];
    const float* bhh0   = (const float*)d_in[6];
    const float* Wpred0 = (const float*)d_in[7];
    const float* bpred0 = (const float*)d_in[8];
    const float* pos0   = (const float*)d_in[9];
    const float* chan0  = (const float*)d_in[10];
    const float* W_emb1 = (const float*)d_in[11];
    const float* b_emb1 = (const float*)d_in[12];
    const float* Wih1   = (const float*)d_in[13];
    const float* Whh1   = (const float*)d_in[14];
    const float* bih1   = (const float*)d_in[15];
    const float* bhh1   = (const float*)d_in[16];
    const float* Wpred1 = (const float*)d_in[17];
    const float* bpred1 = (const float*)d_in[18];
    const float* pos1   = (const float*)d_in[19];
    const float* chan1  = (const float*)d_in[20];
    float* out = (float*)d_out;

    i64 off = 0;
    char* base = (char*)d_ws;
    auto alloc = [&](i64 bytes) -> void* {
        void* p = base + off; off += (bytes + 255) & ~(i64)255; return p;
    };
    float* f_hfrag = (float*)alloc((i64)MP * 512 * 4);   // fragment-layout fp32 h
    u16*   f_hbf   = (u16*)  alloc((i64)MP * 512 * 2);   // row-major bf16 mirror
    u16*   wih0b   = (u16*)  alloc((i64)1536 * 512 * 2);
    u16*   whh0b   = (u16*)  alloc((i64)1536 * 512 * 2);
    u16*   wih1b   = (u16*)  alloc((i64)768 * 256 * 2);
    u16*   whh1b   = (u16*)  alloc((i64)768 * 256 * 2);
    u16*   we0b    = (u16*)  alloc((i64)512 * 64 * 2);
    u16*   we1b    = (u16*)  alloc((i64)256 * 64 * 2);
    u16*   wp0b    = (u16*)  alloc((i64)128 * 512 * 2);
    u16*   wp1b    = (u16*)  alloc((i64)128 * 256 * 2);
    u16*   f_pm0   = (u16*)  alloc((i64)768 * 512 * 2);
    u16*   f_pm1   = (u16*)  alloc((i64)1408 * 256 * 2);
    u16*   f_gidec = (u16*)  alloc((i64)768 * 1536 * 2);
    float* f_y0    = (float*)alloc((i64)NB * 96 * 4);
    float* f_y1    = (float*)alloc((i64)NB * 96 * 4);
    i64 fixed = off;

    // shared region R: layer-0 group bufs OR layer-1 bufs (temporally disjoint)
    char* R = base + fixed;
    i64 a1 = (((i64)4 * MP * 64 * 2) + 255) & ~(i64)255;
    i64 a2 = (((i64)4 * MP * 256 * 2) + 255) & ~(i64)255;
    i64 a3 = (i64)4 * MP * 768 * 2;
    i64 R1 = a1 + a2 + a3;
    u16* f_seg1 = (u16*)R;
    u16* f_xe1  = (u16*)(R + a1);
    u16* f_gi1  = (u16*)(R + a1 + a2);   // fragment-packed, 4 segments
    u16* f_hy   = f_gi1;                  // alias (decoders run after gi use)
    int gsz = 2;
    {
        const int cand[3] = {15, 5, 3};
        for (int ii = 0; ii < 3; ++ii) {
            i64 need = (i64)cand[ii] * MP * (64 + 512 + 1536) * 2 + 3 * 256;
            i64 tot = fixed + (need > R1 ? need : R1);
            if (tot <= (i64)ws_size) { gsz = cand[ii]; break; }
        }
    }
    u16* f_seg0 = (u16*)R;
    i64 s1 = (((i64)gsz * MP * 64 * 2) + 255) & ~(i64)255;
    i64 s2 = (((i64)gsz * MP * 512 * 2) + 255) & ~(i64)255;
    u16* f_xe0 = (u16*)(R + s1);
    u16* f_gi0 = (u16*)(R + s1 + s2);    // fragment-packed, gsz steps

    auto cvt = [&](const float* s, u16* dst, int Rr, int C, int Rp, int Cp) {
        i64 tot = (i64)Rp * Cp;
        convert_pad<<<(int)((tot + 255) / 256), 256, 0, stream>>>(s, dst, Rr, C, Rp, Cp);
    };
    auto gemmN = [&](const u16* A, const u16* B, const float* bias, void* C,
                     int gx, int Nc, int K, int Mstore, int ldc, int mode, int dgate) {
        dim3 g(gx, (Nc + 127) / 128);
        if (mode == 0)      gemm_bf16mfma<0><<<g, 256, 0, stream>>>(A, B, bias, C, K, Mstore, Nc, ldc, dgate);
        else if (mode == 1) gemm_bf16mfma<1><<<g, 256, 0, stream>>>(A, B, bias, C, K, Mstore, Nc, ldc, dgate);
        else if (mode == 2) gemm_bf16mfma<2><<<g, 256, 0, stream>>>(A, B, bias, C, K, Mstore, Nc, ldc, dgate);
        else                gemm_bf16mfma<3><<<g, 256, 0, stream>>>(A, B, bias, C, K, Mstore, Nc, ldc, dgate);
    };

    cvt(Wih0, wih0b, 1536, 512, 1536, 512);
    cvt(Whh0, whh0b, 1536, 512, 1536, 512);
    cvt(Wih1, wih1b, 768, 256, 768, 256);
    cvt(Whh1, whh1b, 768, 256, 768, 256);
    cvt(W_emb0, we0b, 512, 48, 512, 64);
    cvt(W_emb1, we1b, 256, 24, 256, 64);
    cvt(Wpred0, wp0b, 48, 512, 128, 512);
    cvt(Wpred1, wp1b, 24, 256, 128, 256);
    pmat_fill_bf<<<(int)(((i64)768 * 512 + 255) / 256), 256, 0, stream>>>(pos0, chan0, f_pm0, 2, 512, 768);
    pmat_fill_bf<<<(int)(((i64)1408 * 256 + 255) / 256), 256, 0, stream>>>(pos1, chan1, f_pm1, 4, 256, 1408);

    // ================= layer 0: d=512, s=48, 15 steps in groups of gsz ========
    {
        i64 n = (i64)MP * 512;
        zero2_kernel<<<(int)((n + 255) / 256), 256, 0, stream>>>(f_hfrag, f_hbf, n);
    }
    for (int t0 = 0; t0 < 15;) {
        int g = 15 - t0 < gsz ? 15 - t0 : gsz;
        i64 tot = (i64)g * MP * 64;
        seg_gather_bf<<<(int)((tot + 255) / 256), 256, 0, stream>>>(x, f_seg0, t0, g, 48, 64);
        gemmN(f_seg0, we0b, b_emb0, f_xe0, g * 81, 512, 64, g * MP, 512, 2, 0);
        gemmN(f_xe0, wih0b, bih0, f_gi0, g * 81, 1536, 512, 0, 0, 3, 512);   // packed gi
        for (int s = 0; s < g; ++s)
            gru_fused_v2<512, 0><<<dim3(81, 8), 256, 0, stream>>>(
                f_hbf, whh0b, bhh0, f_gi0 + (i64)s * MP * 1536,
                (f32x4*)f_hfrag, f_hbf, nullptr);
        t0 += g;
    }
    // decoder 0
    gemmN(f_pm0, wih0b, bih0, f_gidec, 6, 1536, 512, 642, 1536, 1, 0);
    gru_fused_v2<512, 2><<<dim3(81, 8), 256, 0, stream>>>(
        f_hbf, whh0b, bhh0, f_gidec, (f32x4*)f_hfrag, nullptr, f_hy);
    gemmN(f_hy, wp0b, bpred0, f_y0, 161, 48, 512, 2 * NB, 48, 0, 0);

    // ================= layer 1: d=256, s=24, 60 steps (4 gi segments) =========
    {
        i64 n = (i64)MP * 256;
        zero2_kernel<<<(int)((n + 255) / 256), 256, 0, stream>>>(f_hfrag, f_hbf, n);
    }
    {
        i64 tot = (i64)4 * MP * 64;
        seg_gather_bf<<<(int)((tot + 255) / 256), 256, 0, stream>>>(x, f_seg1, 0, 4, 24, 64);
    }
    gemmN(f_seg1, we1b, b_emb1, f_xe1, 324, 256, 64, 4 * MP, 256, 2, 0);
    gemmN(f_xe1, wih1b, bih1, f_gi1, 324, 768, 256, 0, 0, 3, 256);           // packed gi
    for (int t = 0; t < 60; ++t)
        gru_fused_v2<256, 0><<<dim3(81, 4), 256, 0, stream>>>(
            f_hbf, whh1b, bhh1, f_gi1 + (i64)(t & 3) * MP * 768,
            (f32x4*)f_hfrag, f_hbf, nullptr);
    // decoder 1
    gemmN(f_pm1, wih1b, bih1, f_gidec, 11, 768, 256, 1284, 768, 1, 0);
    gru_fused_v2<256, 4><<<dim3(81, 4), 256, 0, stream>>>(
        f_hbf, whh1b, bhh1, f_gidec, (f32x4*)f_hfrag, nullptr, f_hy);
    gemmN(f_hy, wp1b, bpred1, f_y1, 321, 24, 256, 4 * NB, 24, 0, 0);

    // ================= combine =================
    out_kernel<<<(BATCH_ * PRED_ * ENC_ + 255) / 256, 256, 0, stream>>>(x, f_y0, f_y1, out);
}